// Round 2
// baseline (156.957 us; speedup 1.0000x reference)
//
#include <hip/hip_runtime.h>
#include <hip/hip_bf16.h>
#include <stdint.h>

typedef __attribute__((ext_vector_type(4))) float f32x4;
typedef __attribute__((ext_vector_type(8))) __bf16 bf16x8;

#define NROWS 1000000

__device__ __forceinline__ bf16x8 cvt8(f32x4 a, f32x4 b) {
    bf16x8 r;
    r[0] = (__bf16)a[0]; r[1] = (__bf16)a[1];
    r[2] = (__bf16)a[2]; r[3] = (__bf16)a[3];
    r[4] = (__bf16)b[0]; r[5] = (__bf16)b[1];
    r[6] = (__bf16)b[2]; r[7] = (__bf16)b[3];
    return r;
}

// out[N,64] = relu( concat(x[nidx], ht ? x[tidx] : 0) @ W^T + b )
// MFMA mapping (v_mfma_f32_16x16x32_bf16), operand-swap:
//   A-operand = W fragment:  lane holds W[c][k], c = ct*16 + (lane&15), k = ks*32 + (lane>>4)*8 + e
//   B-operand = gathered x:  lane holds X[r][k], r = g*16 + (lane&15),  k = same map
//   D: col = lane&15 -> output ROW, row = (lane>>4)*4 + reg -> output COL
//   => each lane's 4 accum regs are 4 consecutive out columns -> one float4 store per tile
__global__ void heconv_mfma(const float* __restrict__ x,
                            const int* __restrict__ nidx,
                            const int* __restrict__ tidx,
                            const int* __restrict__ ht,      // bool delivered as int32
                            const float* __restrict__ W,     // [64][128]
                            const float* __restrict__ bias,  // [64]
                            float* __restrict__ out)         // [N][64]
{
    const int lane = threadIdx.x & 63;
    const int wave = threadIdx.x >> 6;   // 0..3
    const int lrow = lane & 15;          // 0..15
    const int lkg  = lane >> 4;          // 0..3

    // W fragments, held in registers for the whole grid-stride loop (16 x 4 VGPR = 64 VGPR)
    bf16x8 wfrag[4][4];
#pragma unroll
    for (int ct = 0; ct < 4; ++ct) {
        const float* wrow = W + (ct * 16 + lrow) * 128 + lkg * 8;
#pragma unroll
        for (int ks = 0; ks < 4; ++ks) {
            f32x4 w0 = *(const f32x4*)(wrow + ks * 32);
            f32x4 w1 = *(const f32x4*)(wrow + ks * 32 + 4);
            wfrag[ct][ks] = cvt8(w0, w1);
        }
    }
    // bias fragment: acc regs are cols ct*16 + lkg*4 + {0..3} -> contiguous float4
    f32x4 bfrag[4];
#pragma unroll
    for (int ct = 0; ct < 4; ++ct)
        bfrag[ct] = *(const f32x4*)(bias + ct * 16 + lkg * 4);

    const int nGroups = NROWS / 16;           // 62500 groups of 16 rows
    const int gstride = gridDim.x * 4;
    for (int g = blockIdx.x * 4 + wave; g < nGroups; g += gstride) {
        const int r  = g * 16 + lrow;         // this lane's output row (j of D)
        const int ni = nidx[r];
        const int ti = tidx[r];
        const bool tw = ht[r] != 0;

        bf16x8 xf[4];
        {
            const float* nrow = x + (size_t)ni * 64 + lkg * 8;
            f32x4 n0 = *(const f32x4*)(nrow);
            f32x4 n1 = *(const f32x4*)(nrow + 4);
            f32x4 n2 = *(const f32x4*)(nrow + 32);
            f32x4 n3 = *(const f32x4*)(nrow + 36);
            xf[0] = cvt8(n0, n1);             // k in [0,32)
            xf[1] = cvt8(n2, n3);             // k in [32,64)
        }
        if (tw) {
            const float* trow = x + (size_t)ti * 64 + lkg * 8;
            f32x4 t0 = *(const f32x4*)(trow);
            f32x4 t1 = *(const f32x4*)(trow + 4);
            f32x4 t2 = *(const f32x4*)(trow + 32);
            f32x4 t3 = *(const f32x4*)(trow + 36);
            xf[2] = cvt8(t0, t1);             // k in [64,96)  -> twin cols 0..31
            xf[3] = cvt8(t2, t3);             // k in [96,128) -> twin cols 32..63
        } else {
            bf16x8 z = { (__bf16)0.f, (__bf16)0.f, (__bf16)0.f, (__bf16)0.f,
                         (__bf16)0.f, (__bf16)0.f, (__bf16)0.f, (__bf16)0.f };
            xf[2] = z;
            xf[3] = z;
        }

#pragma unroll
        for (int ct = 0; ct < 4; ++ct) {
            f32x4 acc = bfrag[ct];
#pragma unroll
            for (int ks = 0; ks < 4; ++ks)
                acc = __builtin_amdgcn_mfma_f32_16x16x32_bf16(wfrag[ct][ks], xf[ks], acc, 0, 0, 0);
            f32x4 o;
            o[0] = fmaxf(acc[0], 0.f);
            o[1] = fmaxf(acc[1], 0.f);
            o[2] = fmaxf(acc[2], 0.f);
            o[3] = fmaxf(acc[3], 0.f);
            *(f32x4*)(out + (size_t)r * 64 + ct * 16 + lkg * 4) = o;
        }
    }
}

extern "C" void kernel_launch(void* const* d_in, const int* in_sizes, int n_in,
                              void* d_out, int out_size, void* d_ws, size_t ws_size,
                              hipStream_t stream) {
    const float* x    = (const float*)d_in[0];
    const int*   ni   = (const int*)d_in[1];
    const int*   ti   = (const int*)d_in[2];
    const int*   ht   = (const int*)d_in[3];
    const float* W    = (const float*)d_in[4];
    const float* bias = (const float*)d_in[5];
    float*       out  = (float*)d_out;

    heconv_mfma<<<2048, 256, 0, stream>>>(x, ni, ti, ht, W, bias, out);
}